// Round 3
// baseline (146.552 us; speedup 1.0000x reference)
//
#include <hip/hip_runtime.h>

// MorphologicalDilation: out[b,i,j,f] = max_{p in 0..8} (x[b, i+p/3, j+p%3, 0] + w[p, f])
// x: (16, 256, 256, 1) fp32, w: (1,1,1,9,32) fp32 -> out: (16, 254, 254, 32) fp32
//
// v4: FILL-SHAPED STORE STREAM. v3 falsified the L2-policy theory (nt stores
// neutral); the remaining structural difference vs the 6.7 TB/s fill on this
// buffer is store shape. Old: each wave-store = 8x128B chunks strided 512B over
// 4KB, k-interleaved. New: lane = px*8+fq with consecutive px per wave -> each
// store instruction is 1KB fully contiguous; block sweeps the row linearly in
// 4KB steps. Keeps RPT=4 i-blocking (6 input rows -> 4 output rows), register w,
// max3 trees. x loads become 3 scalars/row (8-way lane broadcast, L1-resident).

#define BB 16
#define HH 256
#define WW 256
#define FF 32
#define HO 254
#define WO 254
#define RPT 4   // output rows per block (one thread handles all 4 for its pixel)

__device__ __forceinline__ float4 f4add(float a, float4 w) {
    return make_float4(a + w.x, a + w.y, a + w.z, a + w.w);
}
__device__ __forceinline__ float4 f4max(float4 a, float4 b) {
    return make_float4(fmaxf(a.x, b.x), fmaxf(a.y, b.y),
                       fmaxf(a.z, b.z), fmaxf(a.w, b.w));
}

__global__ __launch_bounds__(256) void
dilate_kernel(const float* __restrict__ x, const float* __restrict__ w,
              float* __restrict__ out) {
    const int fq = threadIdx.x & 7;        // filter quad: filters fq*4..fq*4+3
    const int px = threadIdx.x >> 3;       // pixel within 32-px group: CONSECUTIVE
    const int i0 = blockIdx.y * RPT;       // first output row of this block
    const int b  = blockIdx.z;

    // 9 w fragments into registers (reused for all pixels/rows).
    const float4* __restrict__ w4 = (const float4*)w + fq;
    float4 wv[9];
#pragma unroll
    for (int p = 0; p < 9; ++p) wv[p] = w4[p * 8];

    // Clamped input-row base pointers (clamped rows feed only masked outputs).
    const float* __restrict__ xb = x + (size_t)b * HH * WW;
    const float* xr[RPT + 2];
#pragma unroll
    for (int r = 0; r < RPT + 2; ++r) {
        int row = i0 + r;
        row = (row < HH) ? row : (HH - 1);
        xr[r] = xb + row * WW;
    }

    // Sweep the row in 8 steps of 32 consecutive pixels (block covers 4KB/row/step;
    // each wave-store instruction = 64 lanes x 16B = 1KB contiguous).
#pragma unroll 2
    for (int it = 0; it < 8; ++it) {
        const int j  = it * 32 + px;
        const int jl = (j < WO) ? j : (WO - 1);   // load clamp (masked lanes only)

        // 6 rows x 3 cols; 8 lanes per px share addresses (L1 broadcast).
        float xv[RPT + 2][3];
#pragma unroll
        for (int r = 0; r < RPT + 2; ++r) {
            xv[r][0] = xr[r][jl + 0];
            xv[r][1] = xr[r][jl + 1];
            xv[r][2] = xr[r][jl + 2];
        }

#pragma unroll
        for (int rr = 0; rr < RPT; ++rr) {
            const int i = i0 + rr;
            float4 t0, t1, t2;
#pragma unroll
            for (int r = 0; r < 3; ++r) {
                float4 s0 = f4add(xv[rr + r][0], wv[r * 3 + 0]);
                float4 s1 = f4add(xv[rr + r][1], wv[r * 3 + 1]);
                float4 s2 = f4add(xv[rr + r][2], wv[r * 3 + 2]);
                float4 t  = f4max(f4max(s0, s1), s2);   // -> v_max3_f32
                if (r == 0) t0 = t; else if (r == 1) t1 = t; else t2 = t;
            }
            const float4 m = f4max(f4max(t0, t1), t2);  // -> v_max3_f32

            if (j < WO && i < HO) {
                *((float4*)out + (((size_t)(b * HO + i) * WO + j) * 8 + fq)) = m;
            }
        }
    }
}

extern "C" void kernel_launch(void* const* d_in, const int* in_sizes, int n_in,
                              void* d_out, int out_size, void* d_ws, size_t ws_size,
                              hipStream_t stream) {
    const float* x = (const float*)d_in[0];
    const float* w = (const float*)d_in[1];
    float* out = (float*)d_out;

    dim3 grid(1, (HO + RPT - 1) / RPT, BB);   // (1, 64, 16) = 1024 blocks
    dilate_kernel<<<grid, 256, 0, stream>>>(x, w, out);
}